// Round 4
// baseline (151.410 us; speedup 1.0000x reference)
//
#include <hip/hip_runtime.h>

#define BM 128
#define HBN 64
#define TEMP 0.07f

typedef __attribute__((ext_vector_type(4))) float f32x4;
typedef __attribute__((ext_vector_type(4))) int   i32x4;
typedef __attribute__((ext_vector_type(8))) int   i32x8;

// L2-normalize rows of X (fp32, N x 512) -> fp8 e4m3 (1 B/elem). One wave/row.
// Fully coalesced: lane reads float4 [lane] and [lane+64] (contiguous 1 KB/instr).
__global__ __launch_bounds__(256) void knorm(const float* __restrict__ X,
                                             unsigned char* __restrict__ Fq, int D) {
  int row = blockIdx.x * 4 + (threadIdx.x >> 6);
  int lane = threadIdx.x & 63;
  const float4* xr = (const float4*)(X + (size_t)row * D);
  float4 a = xr[lane];        // cols lane*4 .. lane*4+3
  float4 b = xr[lane + 64];   // cols 256+lane*4 ..
  float ss = a.x*a.x + a.y*a.y + a.z*a.z + a.w*a.w
           + b.x*b.x + b.y*b.y + b.z*b.z + b.w*b.w;
  #pragma unroll
  for (int off = 1; off < 64; off <<= 1) ss += __shfl_xor(ss, off, 64);
  float r = rsqrtf(ss);
  int lo = 0, hi = 0;
  lo = __builtin_amdgcn_cvt_pk_fp8_f32(a.x*r, a.y*r, lo, false);
  lo = __builtin_amdgcn_cvt_pk_fp8_f32(a.z*r, a.w*r, lo, true);
  hi = __builtin_amdgcn_cvt_pk_fp8_f32(b.x*r, b.y*r, hi, false);
  hi = __builtin_amdgcn_cvt_pk_fp8_f32(b.z*r, b.w*r, hi, true);
  unsigned char* op = Fq + (size_t)row * D;
  *(int*)(op + lane * 4)       = lo;
  *(int*)(op + 256 + lane * 4) = hi;
}

// Symmetric-GEMM SupCon kernel. sim = Fq*Fq^T is symmetric, so only the
// 2080 unordered 128x128 tile pairs {I,J} are computed (vs 4096 ordered):
// each exp(sim[i,j]) is accumulated into row i's sum (row side) AND row
// j's sum (col side). Halves MFMA, LDS reads, and exp work.
//   enumeration: k<2048: t=k/64, I=k%64, J=(I+t)%64  (t=0 -> diagonal)
//                k>=2048: I=k-2048 (0..31), J=I+32    (half band t=32)
//   partials: psum[slot][row], slot in [0,64): tile {I,J} writes
//   psum[J][I-rows] (row side) and psum[I][J-rows] (col side, skip if diag).
//   Each (slot,row) is written by exactly one block -> deterministic.
// MX-scaled MFMA (scales=1.0, bit-identical to e4m3, 2x rate) as R2.
// B-tile (64 KB) staged once via swizzled global_load_lds; 2 phases of
// 64 cols with counted vmcnt(8)/vmcnt(0) + raw barriers (R2 pipeline).
__global__ __launch_bounds__(256, 1)
void kmain(const unsigned char* __restrict__ F, const int* __restrict__ tgt,
           float* __restrict__ psum, float* __restrict__ pmask, int N, int D) {
  __shared__ __align__(16) unsigned char Bs[2][HBN * 512];  // 64 KB J-tile
  __shared__ float cred[2][4][128];                         // col cross-wave reduce

  const int tid  = threadIdx.x;
  const int lane = tid & 63;
  const int wave = tid >> 6;
  const int quad = lane >> 4;
  const int l15  = lane & 15;

  const int NBLK = N / BM;        // 64
  const int half = NBLK >> 1;     // 32
  const int base = NBLK * half;   // 2048
  int I, J;
  if ((int)blockIdx.x < base) {
    int t = blockIdx.x / NBLK;
    I = blockIdx.x - t * NBLK;
    J = I + t; if (J >= NBLK) J -= NBLK;
  } else {
    I = blockIdx.x - base;
    J = I + half;
  }
  const bool diag = (I == J);
  const int rowbase = I * BM;
  const int colbase = J * BM;

  // ---- A fragments: 2 mi x 4 ksteps x 32 fp8 (i32x8) ----
  i32x8 af[2][4];
  #pragma unroll
  for (int mi = 0; mi < 2; ++mi) {
    const unsigned char* rp = F + (size_t)(rowbase + wave*32 + mi*16 + l15) * 512 + quad*32;
    #pragma unroll
    for (int ks = 0; ks < 4; ++ks) {
      i32x4 lo = *(const i32x4*)(rp + ks*128);
      i32x4 hi = *(const i32x4*)(rp + ks*128 + 16);
      af[mi][ks] = __builtin_shufflevector(lo, hi, 0,1,2,3,4,5,6,7);
    }
  }

  int trow[2][4];
  #pragma unroll
  for (int mi = 0; mi < 2; ++mi)
    #pragma unroll
    for (int r = 0; r < 4; ++r)
      trow[mi][r] = tgt[rowbase + wave*32 + mi*16 + quad*4 + r];

  int tc0[4], tc1[4];
  #pragma unroll
  for (int ni = 0; ni < 4; ++ni) {
    tc0[ni] = tgt[colbase + ni*16 + l15];
    tc1[ni] = tgt[colbase + 64 + ni*16 + l15];
  }

  // stage J tile (128 rows x 512 B); phys 16B-slot p holds logical p^(row&7).
  // it 0..7 -> rows 0..63 (phase 0), it 8..15 -> rows 64..127 (phase 1).
  #pragma unroll
  for (int it = 0; it < 16; ++it) {
    const int L   = it * 256 + tid;
    const int row = L >> 5;
    const int ks  = (L & 31) ^ (row & 7);
    const unsigned char* gp = F + (size_t)(colbase + row) * 512 + ks * 16;
    __builtin_amdgcn_global_load_lds(
        (const __attribute__((address_space(1))) void*)gp,
        (__attribute__((address_space(3))) void*)(&Bs[0][0] + L * 16), 16, 0, 0);
  }

  float se[2][4], ms[2][4];
  #pragma unroll
  for (int mi = 0; mi < 2; ++mi)
    #pragma unroll
    for (int r = 0; r < 4; ++r) { se[mi][r] = 0.f; ms[mi][r] = 0.f; }
  f32x4 ce0 = (f32x4){0,0,0,0}, ce1 = (f32x4){0,0,0,0};
  f32x4 cm0 = (f32x4){0,0,0,0}, cm1 = (f32x4){0,0,0,0};

  const float C1 = (1.0f / TEMP) * 1.4426950408889634f;
  const float C0 = -C1;
  const int sw0 = (quad * 2) ^ (l15 & 7);   // read-side swizzle (row&7 == l15&7)

  auto PHASE = [&](const int g, f32x4& ceg, f32x4& cmg, const int (&tcg)[4]) {
    f32x4 acc[2][4];
    #pragma unroll
    for (int mi = 0; mi < 2; ++mi)
      #pragma unroll
      for (int ni = 0; ni < 4; ++ni)
        acc[mi][ni] = (f32x4){0.f, 0.f, 0.f, 0.f};

    const unsigned char* bb  = &Bs[0][0] + g * (HBN * 512) + l15 * 512;
    const unsigned char* bp0 = bb + sw0 * 16;
    const unsigned char* bp1 = bb + (sw0 ^ 1) * 16;

    #pragma unroll
    for (int ks = 0; ks < 4; ++ks) {
      #pragma unroll
      for (int ni = 0; ni < 4; ++ni) {
        i32x4 b0 = *(const i32x4*)(bp0 + ni*8192 + ks*128);
        i32x4 b1 = *(const i32x4*)(bp1 + ni*8192 + ks*128);
        i32x8 b = __builtin_shufflevector(b0, b1, 0,1,2,3,4,5,6,7);
        acc[0][ni] = __builtin_amdgcn_mfma_scale_f32_16x16x128_f8f6f4(
            af[0][ks], b, acc[0][ni], 0, 0, 0, 0x7F7F7F7F, 0, 0x7F7F7F7F);
        acc[1][ni] = __builtin_amdgcn_mfma_scale_f32_16x16x128_f8f6f4(
            af[1][ks], b, acc[1][ni], 0, 0, 0, 0x7F7F7F7F, 0, 0x7F7F7F7F);
      }
    }

    // fold 32x64 into row partials (se/ms) and col partials (ceg/cmg).
    // col side accumulated unconditionally; diag blocks just don't write it.
    #pragma unroll
    for (int mi = 0; mi < 2; ++mi)
      #pragma unroll
      for (int ni = 0; ni < 4; ++ni)
        #pragma unroll
        for (int r = 0; r < 4; ++r) {
          float v = acc[mi][ni][r];
          float e = __builtin_amdgcn_exp2f(fmaf(v, C1, C0));
          se[mi][r] += e;
          ceg[ni]   += e;
          if (tcg[ni] == trow[mi][r]) { ms[mi][r] += v; cmg[ni] += v; }
        }
  };

  asm volatile("s_waitcnt vmcnt(8)" ::: "memory");  // phase-0 rows + A/tgt loads done
  __builtin_amdgcn_s_barrier();
  PHASE(0, ce0, cm0, tc0);
  asm volatile("s_waitcnt vmcnt(0)" ::: "memory");  // phase-1 rows done
  __builtin_amdgcn_s_barrier();
  PHASE(1, ce1, cm1, tc1);

  // ---- row-side partials -> psum[J][I-rows] ----
  #pragma unroll
  for (int mi = 0; mi < 2; ++mi)
    #pragma unroll
    for (int r = 0; r < 4; ++r) {
      float s = se[mi][r], m = ms[mi][r];
      #pragma unroll
      for (int off = 1; off < 16; off <<= 1) {
        s += __shfl_xor(s, off, 64);
        m += __shfl_xor(m, off, 64);
      }
      if (l15 == 0) {
        int row = rowbase + wave*32 + mi*16 + quad*4 + r;
        psum [(size_t)J * N + row] = s;
        pmask[(size_t)J * N + row] = m;
      }
    }

  // ---- col-side partials -> psum[I][J-rows] (skip for diagonal tiles) ----
  if (!diag) {
    #pragma unroll
    for (int g = 0; g < 2; ++g)
      #pragma unroll
      for (int ni = 0; ni < 4; ++ni) {
        float e = g ? ce1[ni] : ce0[ni];
        float m = g ? cm1[ni] : cm0[ni];
        e += __shfl_xor(e, 16, 64); e += __shfl_xor(e, 32, 64);
        m += __shfl_xor(m, 16, 64); m += __shfl_xor(m, 32, 64);
        if (quad == 0) {
          cred[0][wave][g*64 + ni*16 + l15] = e;
          cred[1][wave][g*64 + ni*16 + l15] = m;
        }
      }
  }
  __syncthreads();
  if (!diag && tid < 128) {
    float s = cred[0][0][tid] + cred[0][1][tid] + cred[0][2][tid] + cred[0][3][tid];
    float m = cred[1][0][tid] + cred[1][1][tid] + cred[1][2][tid] + cred[1][3][tid];
    psum [(size_t)I * N + colbase + tid] = s;
    pmask[(size_t)I * N + colbase + tid] = m;
  }
}

// finalize: 32 blocks x 256 rows; per-block histogram, per-row term,
// wave reduce, one atomicAdd per block into pre-zeroed out.
__global__ __launch_bounds__(256) void kfinal(
    const float* __restrict__ psum, const float* __restrict__ pmask,
    const int* __restrict__ tgt, float* __restrict__ out, int N, int nslot) {
  __shared__ int h[128];
  __shared__ float wsum[4];
  const int tid = threadIdx.x;
  if (tid < 128) h[tid] = 0;
  __syncthreads();
  for (int i = tid; i < N; i += 256) atomicAdd(&h[tgt[i] & 127], 1);
  __syncthreads();

  const int i = blockIdx.x * 256 + tid;
  float s = 0.f, m = 0.f;
  #pragma unroll 8
  for (int sp = 0; sp < nslot; ++sp) {
    s += psum[(size_t)sp * N + i];
    m += pmask[(size_t)sp * N + i];
  }
  const float invT = 1.0f / TEMP;
  float cnt = (float)(h[tgt[i] & 127] - 1);
  float term = (m - 1.0f) * invT / cnt - (logf(s) + invT);
  #pragma unroll
  for (int off = 1; off < 64; off <<= 1) term += __shfl_xor(term, off, 64);
  if ((tid & 63) == 0) wsum[tid >> 6] = term;
  __syncthreads();
  if (tid == 0)
    atomicAdd(out, -(wsum[0] + wsum[1] + wsum[2] + wsum[3]) / (float)N);
}

extern "C" void kernel_launch(void* const* d_in, const int* in_sizes, int n_in,
                              void* d_out, int out_size, void* d_ws, size_t ws_size,
                              hipStream_t stream) {
  const float* X  = (const float*)d_in[0];
  const int* tgt  = (const int*)d_in[1];
  float* out      = (float*)d_out;
  const int N = in_sizes[1];
  const int D = in_sizes[0] / N;
  const int NBLK = N / BM;                              // 64
  const int grid2 = NBLK * (NBLK + 1) / 2;              // 2080

  char* w = (char*)d_ws;
  unsigned char* Fq = (unsigned char*)w;
  size_t off = (size_t)N * D;                           // fp8: 1 B/elem
  float* psum  = (float*)(w + off); off += (size_t)NBLK * N * sizeof(float);
  float* pmask = (float*)(w + off);

  hipMemsetAsync(d_out, 0, sizeof(float), stream);
  knorm<<<N / 4, 256, 0, stream>>>(X, Fq, D);
  kmain<<<grid2, 256, 0, stream>>>(Fq, tgt, psum, pmask, N, D);
  kfinal<<<N / 256, 256, 0, stream>>>(psum, pmask, tgt, out, N, NBLK);
}

// Round 5
// 133.553 us; speedup vs baseline: 1.1337x; 1.1337x over previous
//
#include <hip/hip_runtime.h>

#define TEMP 0.07f
#define NSLOT 41

typedef __attribute__((ext_vector_type(4))) float f32x4;
typedef __attribute__((ext_vector_type(4))) int   i32x4;
typedef __attribute__((ext_vector_type(8))) int   i32x8;

// L2-normalize rows of X (fp32, N x 512) -> fp8 e4m3 (1 B/elem). One wave/row.
__global__ __launch_bounds__(256) void knorm(const float* __restrict__ X,
                                             unsigned char* __restrict__ Fq, int D) {
  int row = blockIdx.x * 4 + (threadIdx.x >> 6);
  int lane = threadIdx.x & 63;
  const float4* xr = (const float4*)(X + (size_t)row * D);
  float4 a = xr[lane];
  float4 b = xr[lane + 64];
  float ss = a.x*a.x + a.y*a.y + a.z*a.z + a.w*a.w
           + b.x*b.x + b.y*b.y + b.z*b.z + b.w*b.w;
  #pragma unroll
  for (int off = 1; off < 64; off <<= 1) ss += __shfl_xor(ss, off, 64);
  float r = rsqrtf(ss);
  int lo = 0, hi = 0;
  lo = __builtin_amdgcn_cvt_pk_fp8_f32(a.x*r, a.y*r, lo, false);
  lo = __builtin_amdgcn_cvt_pk_fp8_f32(a.z*r, a.w*r, lo, true);
  hi = __builtin_amdgcn_cvt_pk_fp8_f32(b.x*r, b.y*r, hi, false);
  hi = __builtin_amdgcn_cvt_pk_fp8_f32(b.z*r, b.w*r, hi, true);
  unsigned char* op = Fq + (size_t)row * D;
  *(int*)(op + lane * 4)       = lo;
  *(int*)(op + 256 + lane * 4) = hi;
}

// Symmetric SupCon GEMM, segmented wrap enumeration (R2 pipeline + R4 math).
// Tiles {I, (I+t)%64}: t=0 diag, t=1..31 all I, t=32 for I<32 -> 2080 tiles.
// Block b<512: I=b&63, t0=4*(b>>6), 4 tiles; b>=512: band, I=b-512, t0=32, 1 tile.
// A (I rows) in registers, reused across the segment. B staged through
// double-buffered 2x32KB LDS halves, 8 pipelined steps with counted
// vmcnt(8) + raw barriers (R2-proven). exp folded into row sums (se/ms)
// and per-tile col sums (ce/cm, in registers, static-indexed).
// Partials: psum[slot][row], slot = tc (0..8) row-side, 8+t (9..40) col-side;
// each (slot,row) written by exactly one block; psum/pmask pre-zeroed.
__global__ __launch_bounds__(256, 1)
void kmain(const unsigned char* __restrict__ F, const int* __restrict__ tgt,
           float* __restrict__ psum, float* __restrict__ pmask, int N, int D) {
  __shared__ __align__(16) unsigned char Bs[2][64 * 512];  // 2 x 32 KB dbuf
  __shared__ float cred[2][4][128];
  __shared__ int tgts[512];

  const int tid  = threadIdx.x;
  const int lane = tid & 63;
  const int wave = tid >> 6;
  const int quad = lane >> 4;
  const int l15  = lane & 15;

  const int b = blockIdx.x;
  int I, t0, ntiles;
  if (b < 512) { I = b & 63; t0 = (b >> 6) * 4; ntiles = 4; }
  else         { I = b - 512; t0 = 32;          ntiles = 1; }
  const int rowbase = I * 128;
  int cb[4];
  #pragma unroll
  for (int c = 0; c < 4; ++c) cb[c] = ((I + t0 + c) & 63) << 7;  // col row-base

  // ---- A fragments: 2 mi x 4 ksteps x 32 fp8 ----
  i32x8 af[2][4];
  #pragma unroll
  for (int mi = 0; mi < 2; ++mi) {
    const unsigned char* rp = F + (size_t)(rowbase + wave*32 + mi*16 + l15) * 512 + quad*32;
    #pragma unroll
    for (int ks = 0; ks < 4; ++ks) {
      i32x4 lo = *(const i32x4*)(rp + ks*128);
      i32x4 hi = *(const i32x4*)(rp + ks*128 + 16);
      af[mi][ks] = __builtin_shufflevector(lo, hi, 0,1,2,3,4,5,6,7);
    }
  }

  int trow[2][4];
  #pragma unroll
  for (int mi = 0; mi < 2; ++mi)
    #pragma unroll
    for (int r = 0; r < 4; ++r)
      trow[mi][r] = tgt[rowbase + wave*32 + mi*16 + quad*4 + r];

  // col targets for the segment's 4 tiles -> LDS (512 ints)
  #pragma unroll
  for (int it = 0; it < 2; ++it) {
    int i = tid + it * 256;
    tgts[i] = tgt[(((I + t0 + (i >> 7)) & 63) << 7) + (i & 127)];
  }

  float se[2][4], ms[2][4];
  #pragma unroll
  for (int mi = 0; mi < 2; ++mi)
    #pragma unroll
    for (int r = 0; r < 4; ++r) { se[mi][r] = 0.f; ms[mi][r] = 0.f; }
  f32x4 ce[4][2], cm[4][2];
  #pragma unroll
  for (int c = 0; c < 4; ++c)
    #pragma unroll
    for (int h = 0; h < 2; ++h) {
      ce[c][h] = (f32x4){0,0,0,0};
      cm[c][h] = (f32x4){0,0,0,0};
    }

  const float C1 = (1.0f / TEMP) * 1.4426950408889634f;
  const float C0 = -C1;
  const int sw0 = (quad * 2) ^ (l15 & 7);

  // stage step s (tile s>>1, half s&1): 64 rows x 512 B into Bs[s&1].
  // phys 16B-slot p in a row holds logical slot p^(row&7).
  auto STAGE = [&](int s) {
    const int rbase = cb[s >> 1] + (s & 1) * 64;
    unsigned char* db = &Bs[0][0] + (s & 1) * 32768;
    #pragma unroll
    for (int it = 0; it < 8; ++it) {
      const int L   = it * 256 + tid;
      const int row = L >> 5;
      const int ks  = (L & 31) ^ (row & 7);
      const unsigned char* gp = F + (size_t)(rbase + row) * 512 + ks * 16;
      __builtin_amdgcn_global_load_lds(
          (const __attribute__((address_space(1))) void*)gp,
          (__attribute__((address_space(3))) void*)(db + L * 16), 16, 0, 0);
    }
  };

  auto COMP = [&](int p) {
    const int c = p >> 1, h = p & 1;
    f32x4 acc[2][4];
    #pragma unroll
    for (int mi = 0; mi < 2; ++mi)
      #pragma unroll
      for (int ni = 0; ni < 4; ++ni)
        acc[mi][ni] = (f32x4){0.f, 0.f, 0.f, 0.f};

    const unsigned char* bb  = &Bs[0][0] + (p & 1) * 32768 + l15 * 512;
    const unsigned char* bp0 = bb + sw0 * 16;
    const unsigned char* bp1 = bb + (sw0 ^ 1) * 16;

    #pragma unroll
    for (int ks = 0; ks < 4; ++ks) {
      #pragma unroll
      for (int ni = 0; ni < 4; ++ni) {
        i32x4 b0 = *(const i32x4*)(bp0 + ni*8192 + ks*128);
        i32x4 b1 = *(const i32x4*)(bp1 + ni*8192 + ks*128);
        i32x8 bv = __builtin_shufflevector(b0, b1, 0,1,2,3,4,5,6,7);
        acc[0][ni] = __builtin_amdgcn_mfma_scale_f32_16x16x128_f8f6f4(
            af[0][ks], bv, acc[0][ni], 0, 0, 0, 0x7F7F7F7F, 0, 0x7F7F7F7F);
        acc[1][ni] = __builtin_amdgcn_mfma_scale_f32_16x16x128_f8f6f4(
            af[1][ks], bv, acc[1][ni], 0, 0, 0, 0x7F7F7F7F, 0, 0x7F7F7F7F);
      }
    }

    int tcg[4];
    #pragma unroll
    for (int ni = 0; ni < 4; ++ni) tcg[ni] = tgts[c*128 + h*64 + ni*16 + l15];
    #pragma unroll
    for (int mi = 0; mi < 2; ++mi)
      #pragma unroll
      for (int ni = 0; ni < 4; ++ni)
        #pragma unroll
        for (int r = 0; r < 4; ++r) {
          float v = acc[mi][ni][r];
          float e = __builtin_amdgcn_exp2f(fmaf(v, C1, C0));
          se[mi][r]    += e;
          ce[c][h][ni] += e;
          if (tcg[ni] == trow[mi][r]) { ms[mi][r] += v; cm[c][h][ni] += v; }
        }
  };

  __syncthreads();            // drain prologue loads; tgts visible
  STAGE(0);                   // 8 loads in flight

  const int lim = 2 * ntiles;
  #pragma unroll
  for (int p = 0; p < 8; ++p) {
    if (p < lim) {            // block-uniform
      if (p + 1 < lim) {
        STAGE(p + 1);         // 16 in flight
        asm volatile("s_waitcnt vmcnt(8)" ::: "memory");  // step p landed
      } else {
        asm volatile("s_waitcnt vmcnt(0)" ::: "memory");
      }
      __builtin_amdgcn_s_barrier();
      COMP(p);
      __builtin_amdgcn_s_barrier();   // buf reads done before next overwrite
    }
  }

  // ---- row-side partials -> slot tc (0..7) or 8 (band) ----
  const int stc = (b < 512) ? (b >> 6) : 8;
  #pragma unroll
  for (int mi = 0; mi < 2; ++mi)
    #pragma unroll
    for (int r = 0; r < 4; ++r) {
      float s = se[mi][r], m = ms[mi][r];
      #pragma unroll
      for (int off = 1; off < 16; off <<= 1) {
        s += __shfl_xor(s, off, 64);
        m += __shfl_xor(m, off, 64);
      }
      if (l15 == 0) {
        int row = rowbase + wave*32 + mi*16 + quad*4 + r;
        psum [(size_t)stc * N + row] = s;
        pmask[(size_t)stc * N + row] = m;
      }
    }

  // ---- col-side partials: tile c -> slot 8 + t0 + c (skip diag t==0) ----
  #pragma unroll
  for (int c = 0; c < 4; ++c) {
    const bool havec = (c < ntiles) && (t0 + c != 0);   // block-uniform
    if (havec) {
      #pragma unroll
      for (int g = 0; g < 2; ++g)
        #pragma unroll
        for (int ni = 0; ni < 4; ++ni) {
          float e = ce[c][g][ni];
          float m = cm[c][g][ni];
          e += __shfl_xor(e, 16, 64); e += __shfl_xor(e, 32, 64);
          m += __shfl_xor(m, 16, 64); m += __shfl_xor(m, 32, 64);
          if (quad == 0) {
            cred[0][wave][g*64 + ni*16 + l15] = e;
            cred[1][wave][g*64 + ni*16 + l15] = m;
          }
        }
    }
    __syncthreads();
    if (havec && tid < 128) {
      float s = cred[0][0][tid] + cred[0][1][tid] + cred[0][2][tid] + cred[0][3][tid];
      float m = cred[1][0][tid] + cred[1][1][tid] + cred[1][2][tid] + cred[1][3][tid];
      const int slot = 8 + t0 + c;
      psum [(size_t)slot * N + cb[c] + tid] = s;
      pmask[(size_t)slot * N + cb[c] + tid] = m;
    }
    __syncthreads();
  }
}

// finalize: 32 blocks x 256 rows; per-block histogram, per-row term,
// wave reduce, one atomicAdd per block into pre-zeroed out.
__global__ __launch_bounds__(256) void kfinal(
    const float* __restrict__ psum, const float* __restrict__ pmask,
    const int* __restrict__ tgt, float* __restrict__ out, int N, int nslot) {
  __shared__ int h[128];
  __shared__ float wsum[4];
  const int tid = threadIdx.x;
  if (tid < 128) h[tid] = 0;
  __syncthreads();
  for (int i = tid; i < N; i += 256) atomicAdd(&h[tgt[i] & 127], 1);
  __syncthreads();

  const int i = blockIdx.x * 256 + tid;
  float s = 0.f, m = 0.f;
  #pragma unroll 8
  for (int sp = 0; sp < nslot; ++sp) {
    s += psum[(size_t)sp * N + i];
    m += pmask[(size_t)sp * N + i];
  }
  const float invT = 1.0f / TEMP;
  float cnt = (float)(h[tgt[i] & 127] - 1);
  float term = (m - 1.0f) * invT / cnt - (logf(s) + invT);
  #pragma unroll
  for (int off = 1; off < 64; off <<= 1) term += __shfl_xor(term, off, 64);
  if ((tid & 63) == 0) wsum[tid >> 6] = term;
  __syncthreads();
  if (tid == 0)
    atomicAdd(out, -(wsum[0] + wsum[1] + wsum[2] + wsum[3]) / (float)N);
}

extern "C" void kernel_launch(void* const* d_in, const int* in_sizes, int n_in,
                              void* d_out, int out_size, void* d_ws, size_t ws_size,
                              hipStream_t stream) {
  const float* X  = (const float*)d_in[0];
  const int* tgt  = (const int*)d_in[1];
  float* out      = (float*)d_out;
  const int N = in_sizes[1];
  const int D = in_sizes[0] / N;

  char* w = (char*)d_ws;
  unsigned char* Fq = (unsigned char*)w;
  size_t off = (size_t)N * D;                           // fp8: 1 B/elem
  float* psum  = (float*)(w + off);
  size_t psz = (size_t)NSLOT * N * sizeof(float);
  off += psz;
  float* pmask = (float*)(w + off);

  hipMemsetAsync(d_out, 0, sizeof(float), stream);
  hipMemsetAsync(psum, 0, 2 * psz, stream);             // slots 8/40 partially covered
  knorm<<<N / 4, 256, 0, stream>>>(X, Fq, D);
  kmain<<<512 + 32, 256, 0, stream>>>(Fq, tgt, psum, pmask, N, D);
  kfinal<<<N / 256, 256, 0, stream>>>(psum, pmask, tgt, out, N, NSLOT);
}